// Round 1
// baseline (983.723 us; speedup 1.0000x reference)
//
#include <hip/hip_runtime.h>
#include <hip/hip_fp16.h>

typedef _Float16 f16;
typedef _Float16 f16x8 __attribute__((ext_vector_type(8)));
typedef _Float16 f16x4 __attribute__((ext_vector_type(4)));
typedef float f32x4 __attribute__((ext_vector_type(4)));

#define LN_EPS 1e-5f

typedef __attribute__((address_space(1))) unsigned int as1_u32;
typedef __attribute__((address_space(3))) unsigned int as3_u32;

__device__ __forceinline__ void gload_lds16(const void* g, void* l) {
    __builtin_amdgcn_global_load_lds((as1_u32*)g, (as3_u32*)l, 16, 0, 0);
}

__device__ __forceinline__ f32x4 mfma16(f16x8 a, f16x8 b, f32x4 c) {
    return __builtin_amdgcn_mfma_f32_16x16x32_f16(a, b, c, 0, 0, 0);
}

// ---------------- conversion kernels ----------------

__global__ void k_cvt4(const float4* __restrict__ in, f16x4* __restrict__ out, int n4) {
    int i = blockIdx.x * blockDim.x + threadIdx.x;
    int st = gridDim.x * blockDim.x;
    for (; i < n4; i += st) {
        float4 v = in[i];
        f16x4 o;
        o.x = (f16)v.x; o.y = (f16)v.y; o.z = (f16)v.z; o.w = (f16)v.w;
        out[i] = o;
    }
}

// W [1024][Nw] f32 row-major -> WT [Nw][1024] f16
__global__ __launch_bounds__(256) void k_transpose_cvt(const float* __restrict__ W,
                                                       f16* __restrict__ WT, int Nw) {
    __shared__ float t[32][33];
    int n0 = blockIdx.x * 32, k0 = blockIdx.y * 32;
    int tx = threadIdx.x & 31, ty = threadIdx.x >> 5;
#pragma unroll
    for (int i = 0; i < 32; i += 8)
        t[ty + i][tx] = W[(size_t)(k0 + ty + i) * Nw + n0 + tx];
    __syncthreads();
#pragma unroll
    for (int i = 0; i < 32; i += 8)
        WT[(size_t)(n0 + ty + i) * 1024 + k0 + tx] = (f16)t[tx][ty + i];
}

// ---------------- main GEMM: C[M][N] = A[M][K] @ Bt[N][K]^T + bias ----------------
// 128x128 tile, BK=64, 4 waves (2x2 of 64x64), f16 MFMA 16x16x32, global_load_lds staging.

template <bool OUTF32>
__global__ __launch_bounds__(256, 2) void k_gemm(const f16* __restrict__ A,
                                                 const f16* __restrict__ Bt,
                                                 void* __restrict__ Cout, int Ncols, int Kd,
                                                 const float* __restrict__ bias1,
                                                 const float* __restrict__ bias2, int bsplit) {
    __shared__ f16 smem[16384];  // As = bytes [0,16K), Bs = [16K,32K)
    const int tid = threadIdx.x, lane = tid & 63, wave = tid >> 6;
    const int m0 = blockIdx.y * 128, n0 = blockIdx.x * 128;
    const size_t ldb = (size_t)Kd * 2;  // row stride in bytes
    f32x4 acc[4][4] = {};

    // staging map: issue i covers rows i*32 + wave*8 + lane/8; 16B slot = lane%8
    const int rA = wave * 8 + (lane >> 3);
    const int slot = (lane & 7) * 16;
    const char* Ab = (const char*)A + (size_t)(m0 + rA) * ldb + slot;
    const char* Bb = (const char*)Bt + (size_t)(n0 + rA) * ldb + slot;
    char* lA = (char*)smem + wave * 1024;
    char* lB = (char*)smem + 16384 + wave * 1024;

    const int wm = (wave & 1) * 64, wn = (wave >> 1) * 64;

    for (int k0 = 0; k0 < Kd; k0 += 64) {
#pragma unroll
        for (int i = 0; i < 4; i++) {
            gload_lds16(Ab + (size_t)k0 * 2 + (size_t)i * 32 * ldb, lA + i * 4096);
            gload_lds16(Bb + (size_t)k0 * 2 + (size_t)i * 32 * ldb, lB + i * 4096);
        }
        __syncthreads();
#pragma unroll
        for (int kk = 0; kk < 64; kk += 32) {
            const int kb = (kk + (lane >> 4) * 8) * 2;
            f16x8 af[4], bf[4];
#pragma unroll
            for (int mi = 0; mi < 4; mi++)
                af[mi] = *(const f16x8*)((const char*)smem + (wm + mi * 16 + (lane & 15)) * 128 + kb);
#pragma unroll
            for (int ni = 0; ni < 4; ni++)
                bf[ni] = *(const f16x8*)((const char*)smem + 16384 + (wn + ni * 16 + (lane & 15)) * 128 + kb);
#pragma unroll
            for (int mi = 0; mi < 4; mi++)
#pragma unroll
                for (int ni = 0; ni < 4; ni++)
                    acc[mi][ni] = mfma16(af[mi], bf[ni], acc[mi][ni]);
        }
        __syncthreads();
    }

    if (!OUTF32) {
        // stage C tile in LDS (reuse smem) for coalesced f16 writes
        f16* Ct = smem;
#pragma unroll
        for (int mi = 0; mi < 4; mi++) {
#pragma unroll
            for (int ni = 0; ni < 4; ni++) {
                const int r = wm + mi * 16 + (lane >> 4) * 4;
                const int c = wn + ni * 16 + (lane & 15);
                const int cg = n0 + c;
                const float bv = (cg < bsplit) ? bias1[cg] : bias2[cg - bsplit];
#pragma unroll
                for (int j = 0; j < 4; j++) Ct[(r + j) * 128 + c] = (f16)(acc[mi][ni][j] + bv);
            }
        }
        __syncthreads();
        f16* Cg = (f16*)Cout;
        const int r = tid >> 1, half = tid & 1;
        const f16* src = Ct + r * 128 + half * 64;
        f16* dst = Cg + (size_t)(m0 + r) * Ncols + n0 + half * 64;
#pragma unroll
        for (int i = 0; i < 8; i++) *(f16x8*)(dst + i * 8) = *(const f16x8*)(src + i * 8);
    } else {
        float* Cg = (float*)Cout;
#pragma unroll
        for (int mi = 0; mi < 4; mi++) {
#pragma unroll
            for (int ni = 0; ni < 4; ni++) {
                const int r = wm + mi * 16 + (lane >> 4) * 4;
                const int c = wn + ni * 16 + (lane & 15);
                const int cg = n0 + c;
                const float bv = (cg < bsplit) ? bias1[cg] : bias2[cg - bsplit];
#pragma unroll
                for (int j = 0; j < 4; j++)
                    Cg[(size_t)(m0 + r + j) * Ncols + cg] = acc[mi][ni][j] + bv;
            }
        }
    }
}

// ---------------- LN row stats over Ckv [65536][1536] ----------------
// stats[row] = {mu_k, rstd_k, mu_v, rstd_v}

__global__ __launch_bounds__(192) void k_rowstats(const f16* __restrict__ Ckv,
                                                  float* __restrict__ stats) {
    const int row = blockIdx.x, t = threadIdx.x;
    const f16x8 v = ((const f16x8*)(Ckv + (size_t)row * 1536))[t];  // t*8 .. t*8+7
    float s = 0.f, s2 = 0.f;
#pragma unroll
    for (int j = 0; j < 8; j++) {
        float x = (float)v[j];
        s += x;
        s2 += x * x;
    }
#pragma unroll
    for (int off = 32; off; off >>= 1) {
        s += __shfl_xor(s, off);
        s2 += __shfl_xor(s2, off);
    }
    __shared__ float red[4];
    const int wave = t >> 6;
    if ((t & 63) == 0 && wave) {
        red[wave * 2 - 2] = s;
        red[wave * 2 - 1] = s2;
    }
    __syncthreads();
    float* st = stats + (size_t)row * 4;
    if (t == 0) {  // k part = cols 0..511 = wave 0
        const float mu = s * (1.0f / 512.0f);
        const float var = s2 * (1.0f / 512.0f) - mu * mu;
        st[0] = mu;
        st[1] = rsqrtf(var + LN_EPS);
    } else if (t == 64) {  // v part = waves 1,2
        const float ss = s + red[2], ss2 = s2 + red[3];
        const float mu = ss * (1.0f / 1024.0f);
        const float var = ss2 * (1.0f / 1024.0f) - mu * mu;
        st[2] = mu;
        st[3] = rsqrtf(var + LN_EPS);
    }
}

// ---------------- column softmax stats (k^T over tokens) ----------------
// partial per (b, slab of 256 rows): pm/ps [8][32][512]

__global__ __launch_bounds__(256) void k_colstats1(const f16* __restrict__ Ckv,
                                                   const float4* __restrict__ stats,
                                                   const float* __restrict__ kg,
                                                   const float* __restrict__ kb,
                                                   float* __restrict__ pm, float* __restrict__ ps) {
    const int b = blockIdx.y, slab = blockIdx.x, t = threadIdx.x;
    const int c0 = t * 2;
    const float g0 = kg[c0], g1 = kg[c0 + 1], e0 = kb[c0], e1 = kb[c0 + 1];
    const size_t r0 = (size_t)b * 8192 + slab * 256;
    float m0 = -1e30f, m1 = -1e30f;
    for (int r = 0; r < 256; r++) {
        const float4 st = stats[r0 + r];
        union { unsigned u; f16 h[2]; } w;
        w.u = *(const unsigned*)(Ckv + (r0 + r) * 1536 + c0);
        const float z0 = ((float)w.h[0] - st.x) * st.y * g0 + e0;
        const float z1 = ((float)w.h[1] - st.x) * st.y * g1 + e1;
        m0 = fmaxf(m0, z0);
        m1 = fmaxf(m1, z1);
    }
    float s0 = 0.f, s1 = 0.f;
    for (int r = 0; r < 256; r++) {
        const float4 st = stats[r0 + r];
        union { unsigned u; f16 h[2]; } w;
        w.u = *(const unsigned*)(Ckv + (r0 + r) * 1536 + c0);
        const float z0 = ((float)w.h[0] - st.x) * st.y * g0 + e0;
        const float z1 = ((float)w.h[1] - st.x) * st.y * g1 + e1;
        s0 += __expf(z0 - m0);
        s1 += __expf(z1 - m1);
    }
    const int o = (b * 32 + slab) * 512 + c0;
    pm[o] = m0; pm[o + 1] = m1;
    ps[o] = s0; ps[o + 1] = s1;
}

__global__ void k_colstats2(const float* __restrict__ pm, const float* __restrict__ ps,
                            float* __restrict__ Mx, float* __restrict__ invZ) {
    const int idx = blockIdx.x * 256 + threadIdx.x;  // 0..4095
    const int b = idx >> 9, c = idx & 511;
    float M = -1e30f;
    for (int s = 0; s < 32; s++) M = fmaxf(M, pm[(b * 32 + s) * 512 + c]);
    float S = 0.f;
    for (int s = 0; s < 32; s++) S += ps[(b * 32 + s) * 512 + c] * __expf(pm[(b * 32 + s) * 512 + c] - M);
    Mx[idx] = M;
    invZ[idx] = 1.0f / S;
}

// ---------------- kv einsum: kv[bh][l][d] partials over token splits ----------------
// A = exp(LN(k)-Mx) [64 x tokens], B = LN(v) [tokens x 128]; MFMA over token dim.

__global__ __launch_bounds__(256, 2) void k_kv(const f16* __restrict__ Ckv,
                                               const float4* __restrict__ stats,
                                               const float* __restrict__ kg,
                                               const float* __restrict__ kbe,
                                               const float* __restrict__ vg,
                                               const float* __restrict__ vbe,
                                               const float* __restrict__ Mx,
                                               float* __restrict__ kvpart) {
    __shared__ f16 As[64 * 64];    // [latent c][token t]
    __shared__ f16 Vs[128 * 64];   // [d][token t]
    __shared__ float cgk[64], cbk[64], cmx[64], cgv[128], cbv[128];
    const int split = blockIdx.x, bh = blockIdx.y;
    const int b = bh >> 3, h = bh & 7;
    const int tid = threadIdx.x, lane = tid & 63, wave = tid >> 6;
    if (tid < 64) {
        cgk[tid] = kg[h * 64 + tid];
        cbk[tid] = kbe[h * 64 + tid];
        cmx[tid] = Mx[b * 512 + h * 64 + tid];
    }
    if (tid < 128) {
        cgv[tid] = vg[h * 128 + tid];
        cbv[tid] = vbe[h * 128 + tid];
    }
    __syncthreads();
    f32x4 acc[8] = {};
    const size_t base = (size_t)b * 8192 + split * 1024;
    for (int t0 = 0; t0 < 1024; t0 += 64) {
        {  // stage exp(LN(k)) tile: threads (g=c-group 0..7, p=token-pair 0..31)
            const int g = tid & 7, p = tid >> 3;
            const size_t row = base + t0 + 2 * p;
            const f16x8 x0 = *(const f16x8*)(Ckv + row * 1536 + h * 64 + g * 8);
            const f16x8 x1 = *(const f16x8*)(Ckv + (row + 1) * 1536 + h * 64 + g * 8);
            const float4 s0 = stats[row], s1 = stats[row + 1];
#pragma unroll
            for (int j = 0; j < 8; j++) {
                const int c = g * 8 + j;
                const float z0 = ((float)x0[j] - s0.x) * s0.y * cgk[c] + cbk[c] - cmx[c];
                const float z1 = ((float)x1[j] - s1.x) * s1.y * cgk[c] + cbk[c] - cmx[c];
                union { unsigned u; f16 h2[2]; } pk;
                pk.h2[0] = (f16)__expf(z0);
                pk.h2[1] = (f16)__expf(z1);
                *(unsigned*)((char*)As + c * 128 + 4 * p) = pk.u;
            }
        }
#pragma unroll
        for (int sub = 0; sub < 2; sub++) {  // stage LN(v) tile
            const int idx = tid + sub * 256;
            const int g = idx & 15, p = idx >> 4;
            const size_t row = base + t0 + 2 * p;
            const f16x8 x0 = *(const f16x8*)(Ckv + row * 1536 + 512 + h * 128 + g * 8);
            const f16x8 x1 = *(const f16x8*)(Ckv + (row + 1) * 1536 + 512 + h * 128 + g * 8);
            const float4 s0 = stats[row], s1 = stats[row + 1];
#pragma unroll
            for (int j = 0; j < 8; j++) {
                const int d = g * 8 + j;
                const float z0 = ((float)x0[j] - s0.z) * s0.w * cgv[d] + cbv[d];
                const float z1 = ((float)x1[j] - s1.z) * s1.w * cgv[d] + cbv[d];
                union { unsigned u; f16 h2[2]; } pk;
                pk.h2[0] = (f16)z0;
                pk.h2[1] = (f16)z1;
                *(unsigned*)((char*)Vs + d * 128 + 4 * p) = pk.u;
            }
        }
        __syncthreads();
#pragma unroll
        for (int kk = 0; kk < 64; kk += 32) {
            const int kb2 = (kk + (lane >> 4) * 8) * 2;
            const f16x8 af = *(const f16x8*)((const char*)As + (wave * 16 + (lane & 15)) * 128 + kb2);
#pragma unroll
            for (int ni = 0; ni < 8; ni++) {
                const f16x8 bf = *(const f16x8*)((const char*)Vs + (ni * 16 + (lane & 15)) * 128 + kb2);
                acc[ni] = mfma16(af, bf, acc[ni]);
            }
        }
        __syncthreads();
    }
    float* out = kvpart + ((size_t)split * 64 + bh) * 8192;
    const int l = wave * 16 + (lane >> 4) * 4;
#pragma unroll
    for (int ni = 0; ni < 8; ni++) {
        const int d = ni * 16 + (lane & 15);
#pragma unroll
        for (int j = 0; j < 4; j++) out[(l + j) * 128 + d] = acc[ni][j];
    }
}

// reduce 8 splits, apply 1/Z, write kvT [bh][d][l] f16
__global__ void k_kvreduce(const float* __restrict__ kvpart, const float* __restrict__ invZ,
                           f16* __restrict__ kvT) {
    const int idx = blockIdx.x * 256 + threadIdx.x;  // 0..524287
    const int d = idx & 127, l = (idx >> 7) & 63, bh = idx >> 13;
    const int b = bh >> 3, h = bh & 7;
    float s = 0.f;
#pragma unroll
    for (int sp = 0; sp < 8; sp++) s += kvpart[((size_t)sp * 64 + bh) * 8192 + l * 128 + d];
    s *= invZ[b * 512 + h * 64 + l];
    kvT[((size_t)bh * 128 + d) * 64 + l] = (f16)s;
}

// ---------------- q: LN + per-head softmax ----------------
// one block per row (512 threads = 8 waves; wave h = head h's 64 latent cols)

__global__ __launch_bounds__(512) void k_qsm(const f16* __restrict__ qlin,
                                             const float* __restrict__ qg,
                                             const float* __restrict__ qbeta,
                                             f16* __restrict__ qsm) {
    const int row = blockIdx.x, t = threadIdx.x;
    const float x = (float)qlin[(size_t)row * 512 + t];
    float s = x, s2 = x * x;
#pragma unroll
    for (int off = 32; off; off >>= 1) {
        s += __shfl_xor(s, off);
        s2 += __shfl_xor(s2, off);
    }
    __shared__ float rs[16];
    const int wave = t >> 6, lane = t & 63;
    if (lane == 0) {
        rs[wave] = s;
        rs[8 + wave] = s2;
    }
    __syncthreads();
    float S = 0.f, S2 = 0.f;
#pragma unroll
    for (int w = 0; w < 8; w++) {
        S += rs[w];
        S2 += rs[8 + w];
    }
    const float mu = S * (1.0f / 512.0f);
    const float var = S2 * (1.0f / 512.0f) - mu * mu;
    const float z = (x - mu) * rsqrtf(var + LN_EPS) * qg[t] + qbeta[t];
    float m = z;
#pragma unroll
    for (int off = 32; off; off >>= 1) m = fmaxf(m, __shfl_xor(m, off));
    const float e = __expf(z - m);
    float se = e;
#pragma unroll
    for (int off = 32; off; off >>= 1) se += __shfl_xor(se, off);
    qsm[(size_t)row * 512 + t] = (f16)(e / se);
}

// ---------------- out_mid[b,m,h*128+d] = sum_l qsm * kvT ----------------

__global__ __launch_bounds__(256) void k_qkv(const f16* __restrict__ qsm,
                                             const f16* __restrict__ kvT,
                                             f16* __restrict__ omid) {
    const int ms = blockIdx.x, bh = blockIdx.y;
    const int b = bh >> 3, h = bh & 7;
    const int tid = threadIdx.x, lane = tid & 63, wave = tid >> 6;
    const int mr = ms * 64 + wave * 16;
    f32x4 acc[8] = {};
    const f16* Ab = qsm + (size_t)(b * 256 + mr + (lane & 15)) * 512 + h * 64;
    const f16* Bb = kvT + (size_t)bh * 8192;
#pragma unroll
    for (int kk = 0; kk < 64; kk += 32) {
        const int k = kk + (lane >> 4) * 8;
        const f16x8 af = *(const f16x8*)(Ab + k);
#pragma unroll
        for (int ni = 0; ni < 8; ni++) {
            const f16x8 bf = *(const f16x8*)(Bb + (ni * 16 + (lane & 15)) * 64 + k);
            acc[ni] = mfma16(af, bf, acc[ni]);
        }
    }
    const int r = b * 256 + mr + (lane >> 4) * 4;
#pragma unroll
    for (int ni = 0; ni < 8; ni++) {
        const int d = h * 128 + ni * 16 + (lane & 15);
#pragma unroll
        for (int j = 0; j < 4; j++) omid[(size_t)(r + j) * 1024 + d] = (f16)acc[ni][j];
    }
}

// ---------------- launch ----------------

extern "C" void kernel_launch(void* const* d_in, const int* in_sizes, int n_in,
                              void* d_out, int out_size, void* d_ws, size_t ws_size,
                              hipStream_t stream) {
    const float* input  = (const float*)d_in[0];
    const float* query  = (const float*)d_in[1];
    const float* q_w    = (const float*)d_in[2];
    const float* q_b    = (const float*)d_in[3];
    const float* q_g    = (const float*)d_in[4];
    const float* q_beta = (const float*)d_in[5];
    const float* k_w    = (const float*)d_in[6];
    const float* k_b    = (const float*)d_in[7];
    const float* k_g    = (const float*)d_in[8];
    const float* k_beta = (const float*)d_in[9];
    const float* v_w    = (const float*)d_in[10];
    const float* v_b    = (const float*)d_in[11];
    const float* v_g    = (const float*)d_in[12];
    const float* v_beta = (const float*)d_in[13];
    const float* proj_w = (const float*)d_in[14];
    const float* proj_b = (const float*)d_in[15];

    char* ws = (char*)d_ws;
    size_t off = 0;
    auto alloc = [&](size_t bytes) {
        char* p = ws + off;
        off += (bytes + 255) & ~(size_t)255;
        return p;
    };
    f16*   A16    = (f16*)alloc((size_t)67108864 * 2);   // input f16
    f16*   Q16    = (f16*)alloc((size_t)2097152 * 2);    // query f16
    f16*   BkvT   = (f16*)alloc((size_t)1536 * 1024 * 2);// [k_w;v_w]^T
    f16*   qwT    = (f16*)alloc((size_t)512 * 1024 * 2);
    f16*   pwT    = (f16*)alloc((size_t)1024 * 1024 * 2);
    f16*   Ckv    = (f16*)alloc((size_t)65536 * 1536 * 2);
    float* stats  = (float*)alloc((size_t)65536 * 16);
    float* pm     = (float*)alloc((size_t)8 * 32 * 512 * 4);
    float* ps     = (float*)alloc((size_t)8 * 32 * 512 * 4);
    float* Mx     = (float*)alloc((size_t)8 * 512 * 4);
    float* invZ   = (float*)alloc((size_t)8 * 512 * 4);
    f16*   qlin   = (f16*)alloc((size_t)2048 * 512 * 2);
    f16*   qsm    = (f16*)alloc((size_t)2048 * 512 * 2);
    float* kvpart = (float*)alloc((size_t)8 * 64 * 64 * 128 * 4);
    f16*   kvT    = (f16*)alloc((size_t)64 * 128 * 64 * 2);
    f16*   omid   = (f16*)alloc((size_t)2048 * 1024 * 2);
    (void)ws_size; (void)in_sizes; (void)n_in; (void)out_size;

    // 1) converts + weight transposes
    k_cvt4<<<2048, 256, 0, stream>>>((const float4*)input, (f16x4*)A16, 16777216);
    k_cvt4<<<512, 256, 0, stream>>>((const float4*)query, (f16x4*)Q16, 524288);
    k_transpose_cvt<<<dim3(16, 32), 256, 0, stream>>>(k_w, BkvT, 512);
    k_transpose_cvt<<<dim3(32, 32), 256, 0, stream>>>(v_w, BkvT + (size_t)512 * 1024, 1024);
    k_transpose_cvt<<<dim3(16, 32), 256, 0, stream>>>(q_w, qwT, 512);
    k_transpose_cvt<<<dim3(32, 32), 256, 0, stream>>>(proj_w, pwT, 1024);

    // 2) fused K/V projection GEMM -> Ckv [65536][1536] (k cols 0..511, v cols 512..1535)
    k_gemm<false><<<dim3(12, 512), 256, 0, stream>>>(A16, BkvT, Ckv, 1536, 1024, k_b, v_b, 512);

    // 3) row LN stats
    k_rowstats<<<65536, 192, 0, stream>>>(Ckv, stats);

    // 4) column softmax stats for k^T
    k_colstats1<<<dim3(32, 8), 256, 0, stream>>>(Ckv, (const float4*)stats, k_g, k_beta, pm, ps);
    k_colstats2<<<16, 256, 0, stream>>>(pm, ps, Mx, invZ);

    // 5) kv einsum + reduce
    k_kv<<<dim3(8, 64), 256, 0, stream>>>(Ckv, (const float4*)stats, k_g, k_beta, v_g, v_beta, Mx, kvpart);
    k_kvreduce<<<2048, 256, 0, stream>>>(kvpart, invZ, kvT);

    // 6) q path: GEMM -> LN+softmax -> out_mid -> final proj (f32 out)
    k_gemm<false><<<dim3(4, 16), 256, 0, stream>>>(Q16, qwT, qlin, 512, 1024, q_b, q_b, 512);
    k_qsm<<<2048, 512, 0, stream>>>(qlin, q_g, q_beta, qsm);
    k_qkv<<<dim3(4, 64), 256, 0, stream>>>(qsm, kvT, omid);
    k_gemm<true><<<dim3(8, 16), 256, 0, stream>>>(omid, pwT, d_out, 1024, 1024, proj_b, proj_b, 2048);
}

// Round 2
// 897.936 us; speedup vs baseline: 1.0955x; 1.0955x over previous
//
#include <hip/hip_runtime.h>
#include <hip/hip_fp16.h>

typedef _Float16 f16;
typedef _Float16 f16x8 __attribute__((ext_vector_type(8)));
typedef _Float16 f16x4 __attribute__((ext_vector_type(4)));
typedef float f32x4 __attribute__((ext_vector_type(4)));

#define LN_EPS 1e-5f

typedef __attribute__((address_space(1))) unsigned int as1_u32;
typedef __attribute__((address_space(3))) unsigned int as3_u32;

__device__ __forceinline__ void gload_lds16(const void* g, void* l) {
    __builtin_amdgcn_global_load_lds((as1_u32*)g, (as3_u32*)l, 16, 0, 0);
}

__device__ __forceinline__ f32x4 mfma16(f16x8 a, f16x8 b, f32x4 c) {
    return __builtin_amdgcn_mfma_f32_16x16x32_f16(a, b, c, 0, 0, 0);
}

// ---------------- conversion: input + query f32 -> f16 in one launch ----------------

__global__ void k_cvt_dual(const float4* __restrict__ in0, const float4* __restrict__ in1,
                           f16x4* __restrict__ out0, f16x4* __restrict__ out1,
                           int nsplit, int ntot) {
    int i = blockIdx.x * blockDim.x + threadIdx.x;
    int st = gridDim.x * blockDim.x;
    for (; i < ntot; i += st) {
        const bool lo = i < nsplit;
        const float4 v = lo ? in0[i] : in1[i - nsplit];
        f16x4 o;
        o.x = (f16)v.x; o.y = (f16)v.y; o.z = (f16)v.z; o.w = (f16)v.w;
        if (lo) out0[i] = o; else out1[i - nsplit] = o;
    }
}

// all 4 weight transposes ([1024][Nw] f32 -> [Nw][1024] f16) in one launch
__global__ __launch_bounds__(256) void k_transpose_all(const float* __restrict__ kw,
                                                       const float* __restrict__ vw,
                                                       const float* __restrict__ qw,
                                                       const float* __restrict__ pw,
                                                       f16* __restrict__ BkvT,
                                                       f16* __restrict__ qwT,
                                                       f16* __restrict__ pwT) {
    __shared__ float t[32][33];
    const int x = blockIdx.x;
    const float* W; f16* WT; int Nw, nt0;
    if (x < 16)      { W = kw; WT = BkvT;                     Nw = 512;  nt0 = x; }
    else if (x < 48) { W = vw; WT = BkvT + (size_t)512 * 1024; Nw = 1024; nt0 = x - 16; }
    else if (x < 64) { W = qw; WT = qwT;                      Nw = 512;  nt0 = x - 48; }
    else             { W = pw; WT = pwT;                      Nw = 1024; nt0 = x - 64; }
    const int n0 = nt0 * 32, k0 = blockIdx.y * 32;
    const int tx = threadIdx.x & 31, ty = threadIdx.x >> 5;
#pragma unroll
    for (int i = 0; i < 32; i += 8)
        t[ty + i][tx] = W[(size_t)(k0 + ty + i) * Nw + n0 + tx];
    __syncthreads();
#pragma unroll
    for (int i = 0; i < 32; i += 8)
        WT[(size_t)(n0 + ty + i) * 1024 + k0 + tx] = (f16)t[tx][ty + i];
}

// ---------------- big K/V GEMM: Ckv[65536][1536] = A16[65536][1024] @ BkvT^T + bias ----
// 256x256 tile, BK=64, 8 waves (2x4), double-buffered LDS (128 KiB), counted vmcnt,
// T2 XOR slot swizzle, T5 setprio, T1 XCD-bijective block swizzle. Grid = 1536 (6 x 256).

__global__ __launch_bounds__(512, 2) void k_gemm256(const f16* __restrict__ A,
                                                    const f16* __restrict__ Bt,
                                                    f16* __restrict__ C,
                                                    const float* __restrict__ bias1,
                                                    const float* __restrict__ bias2) {
    extern __shared__ char lds[];
    const int tid = threadIdx.x, lane = tid & 63, w = tid >> 6;
    const int wr = w >> 2, wc = w & 3;
    const int lane15 = lane & 15, l4 = lane >> 4;

    // bijective XCD swizzle: 1536 = 8 * 192; consecutive swz share the A-panel (by)
    const int swz = ((int)blockIdx.x & 7) * 192 + ((int)blockIdx.x >> 3);
    const int bx = swz % 6, by = swz / 6;
    const size_t m0 = (size_t)by * 256, n0g = (size_t)bx * 256;

    // staging: wave w covers tile rows [w*32, w*32+32); lane L -> row +(L>>3), k-slot (L&7)^(L>>3)
    const int lrow = lane >> 3;
    const int slot = (lane & 7) ^ lrow;
    const int rw = w * 32;
    const f16* gA = A + (m0 + rw + lrow) * 1024 + slot * 8;
    const f16* gB = Bt + (n0g + rw + lrow) * 1024 + slot * 8;
    const int ldsw = rw * 128;  // byte offset of wave's stage block inside a buffer

    // fragment-read constants: LDS slot s holds global slot s ^ (row&7)
    const int sf = l4 ^ (lane15 & 7);
    const int offA = (wr * 128 + lane15) * 128 + sf * 16;
    const int offB = (wc * 64 + lane15) * 128 + sf * 16;

    f32x4 acc[8][4] = {};

#define STAGE(t, bsel)                                                          \
    {                                                                           \
        const int k0s = (t) * 64;                                               \
        char* dA = lds + ((bsel) << 15) + ldsw;                                 \
        char* dB = lds + 65536 + ((bsel) << 15) + ldsw;                         \
        _Pragma("unroll")                                                       \
        for (int i = 0; i < 4; i++) {                                           \
            gload_lds16(gA + (size_t)i * 8192 + k0s, dA + i * 1024);            \
            gload_lds16(gB + (size_t)i * 8192 + k0s, dB + i * 1024);            \
        }                                                                       \
    }

    STAGE(0, 0)
    STAGE(1, 1)
    asm volatile("s_waitcnt vmcnt(8)" ::: "memory");
    __builtin_amdgcn_s_barrier();

    for (int t = 0; t < 16; ++t) {
        const int bsel = t & 1;
        const char* pA = lds + (bsel << 15);
        const char* pB = lds + 65536 + (bsel << 15);
#pragma unroll
        for (int q = 0; q < 4; ++q) {
            const int mh = (q >> 1) * 4, nh = (q & 1) * 2;
            f16x8 af[4][2], bf[2][2];
#pragma unroll
            for (int mi = 0; mi < 4; mi++)
#pragma unroll
                for (int kk = 0; kk < 2; kk++)
                    af[mi][kk] = *(const f16x8*)(pA + ((offA + (mh + mi) * 2048) ^ (kk << 6)));
#pragma unroll
            for (int ni = 0; ni < 2; ni++)
#pragma unroll
                for (int kk = 0; kk < 2; kk++)
                    bf[ni][kk] = *(const f16x8*)(pB + ((offB + (nh + ni) * 2048) ^ (kk << 6)));
            __builtin_amdgcn_s_setprio(1);
#pragma unroll
            for (int mi = 0; mi < 4; mi++)
#pragma unroll
                for (int ni = 0; ni < 2; ni++)
#pragma unroll
                    for (int kk = 0; kk < 2; kk++)
                        acc[mh + mi][nh + ni] =
                            mfma16(af[mi][kk], bf[ni][kk], acc[mh + mi][nh + ni]);
            __builtin_amdgcn_s_setprio(0);
        }
        __builtin_amdgcn_s_barrier();  // all waves done reading buf[bsel]
        if (t < 14) {
            STAGE(t + 2, bsel)                              // overwrite just-freed buffer
            asm volatile("s_waitcnt vmcnt(8)" ::: "memory");  // K-tile t+1 landed; t+2 in flight
        } else {
            asm volatile("s_waitcnt vmcnt(0)" ::: "memory");
        }
        __builtin_amdgcn_s_barrier();  // buf[bsel^1] visible to all waves
    }
#undef STAGE

    // epilogue: stage C tile (256x256 f16 = 128 KiB, reuses LDS) then coalesced copy-out
    {
        f16* Ct = (f16*)lds;
#pragma unroll
        for (int mi = 0; mi < 8; mi++) {
#pragma unroll
            for (int ni = 0; ni < 4; ni++) {
                const int row = wr * 128 + mi * 16 + l4 * 4;
                const int col = wc * 64 + ni * 16 + lane15;
                const int cg = (int)n0g + col;
                const float bv = (cg < 512) ? bias1[cg] : bias2[cg - 512];
#pragma unroll
                for (int j = 0; j < 4; j++)
                    Ct[(row + j) * 256 + col] = (f16)(acc[mi][ni][j] + bv);
            }
        }
        asm volatile("s_waitcnt lgkmcnt(0)" ::: "memory");
        __builtin_amdgcn_s_barrier();
#pragma unroll
        for (int it = 0; it < 16; it++) {
            const int flat = it * 512 + tid;  // 16B chunks; 32 chunks per 256-col row
            const int row = flat >> 5;
            const int ce = (flat & 31) * 8;
            *(f16x8*)(C + (m0 + row) * 1536 + n0g + ce) = *(const f16x8*)(Ct + row * 256 + ce);
        }
    }
}

// ---------------- small GEMM (q / proj): 128x128 tile, m97-style ----------------

template <bool OUTF32>
__global__ __launch_bounds__(256, 2) void k_gemm(const f16* __restrict__ A,
                                                 const f16* __restrict__ Bt,
                                                 void* __restrict__ Cout, int Ncols, int Kd,
                                                 const float* __restrict__ bias1,
                                                 const float* __restrict__ bias2, int bsplit) {
    __shared__ f16 smem[16384];
    const int tid = threadIdx.x, lane = tid & 63, wave = tid >> 6;
    const int m0 = blockIdx.y * 128, n0 = blockIdx.x * 128;
    const size_t ldb = (size_t)Kd * 2;
    f32x4 acc[4][4] = {};

    const int rA = wave * 8 + (lane >> 3);
    const int slot = (lane & 7) * 16;
    const char* Ab = (const char*)A + (size_t)(m0 + rA) * ldb + slot;
    const char* Bb = (const char*)Bt + (size_t)(n0 + rA) * ldb + slot;
    char* lA = (char*)smem + wave * 1024;
    char* lB = (char*)smem + 16384 + wave * 1024;

    const int wm = (wave & 1) * 64, wn = (wave >> 1) * 64;

    for (int k0 = 0; k0 < Kd; k0 += 64) {
#pragma unroll
        for (int i = 0; i < 4; i++) {
            gload_lds16(Ab + (size_t)k0 * 2 + (size_t)i * 32 * ldb, lA + i * 4096);
            gload_lds16(Bb + (size_t)k0 * 2 + (size_t)i * 32 * ldb, lB + i * 4096);
        }
        __syncthreads();
#pragma unroll
        for (int kk = 0; kk < 64; kk += 32) {
            const int kb = (kk + (lane >> 4) * 8) * 2;
            f16x8 af[4], bf[4];
#pragma unroll
            for (int mi = 0; mi < 4; mi++)
                af[mi] = *(const f16x8*)((const char*)smem + (wm + mi * 16 + (lane & 15)) * 128 + kb);
#pragma unroll
            for (int ni = 0; ni < 4; ni++)
                bf[ni] = *(const f16x8*)((const char*)smem + 16384 + (wn + ni * 16 + (lane & 15)) * 128 + kb);
#pragma unroll
            for (int mi = 0; mi < 4; mi++)
#pragma unroll
                for (int ni = 0; ni < 4; ni++)
                    acc[mi][ni] = mfma16(af[mi], bf[ni], acc[mi][ni]);
        }
        __syncthreads();
    }

    if (!OUTF32) {
        f16* Ct = smem;
#pragma unroll
        for (int mi = 0; mi < 4; mi++) {
#pragma unroll
            for (int ni = 0; ni < 4; ni++) {
                const int r = wm + mi * 16 + (lane >> 4) * 4;
                const int c = wn + ni * 16 + (lane & 15);
                const int cg = n0 + c;
                const float bv = (cg < bsplit) ? bias1[cg] : bias2[cg - bsplit];
#pragma unroll
                for (int j = 0; j < 4; j++) Ct[(r + j) * 128 + c] = (f16)(acc[mi][ni][j] + bv);
            }
        }
        __syncthreads();
        f16* Cg = (f16*)Cout;
        const int r = tid >> 1, half = tid & 1;
        const f16* src = Ct + r * 128 + half * 64;
        f16* dst = Cg + (size_t)(m0 + r) * Ncols + n0 + half * 64;
#pragma unroll
        for (int i = 0; i < 8; i++) *(f16x8*)(dst + i * 8) = *(const f16x8*)(src + i * 8);
    } else {
        float* Cg = (float*)Cout;
#pragma unroll
        for (int mi = 0; mi < 4; mi++) {
#pragma unroll
            for (int ni = 0; ni < 4; ni++) {
                const int r = wm + mi * 16 + (lane >> 4) * 4;
                const int c = wn + ni * 16 + (lane & 15);
                const int cg = n0 + c;
                const float bv = (cg < bsplit) ? bias1[cg] : bias2[cg - bsplit];
#pragma unroll
                for (int j = 0; j < 4; j++)
                    Cg[(size_t)(m0 + r + j) * Ncols + cg] = acc[mi][ni][j] + bv;
            }
        }
    }
}

// ---------------- LN row stats over Ckv [65536][1536] ----------------

__global__ __launch_bounds__(192) void k_rowstats(const f16* __restrict__ Ckv,
                                                  float* __restrict__ stats) {
    const int row = blockIdx.x, t = threadIdx.x;
    const f16x8 v = ((const f16x8*)(Ckv + (size_t)row * 1536))[t];
    float s = 0.f, s2 = 0.f;
#pragma unroll
    for (int j = 0; j < 8; j++) {
        float x = (float)v[j];
        s += x;
        s2 += x * x;
    }
#pragma unroll
    for (int off = 32; off; off >>= 1) {
        s += __shfl_xor(s, off);
        s2 += __shfl_xor(s2, off);
    }
    __shared__ float red[4];
    const int wave = t >> 6;
    if ((t & 63) == 0 && wave) {
        red[wave * 2 - 2] = s;
        red[wave * 2 - 1] = s2;
    }
    __syncthreads();
    float* st = stats + (size_t)row * 4;
    if (t == 0) {
        const float mu = s * (1.0f / 512.0f);
        const float var = s2 * (1.0f / 512.0f) - mu * mu;
        st[0] = mu;
        st[1] = rsqrtf(var + LN_EPS);
    } else if (t == 64) {
        const float ss = s + red[2], ss2 = s2 + red[3];
        const float mu = ss * (1.0f / 1024.0f);
        const float var = ss2 * (1.0f / 1024.0f) - mu * mu;
        st[2] = mu;
        st[3] = rsqrtf(var + LN_EPS);
    }
}

// ---------------- column softmax stats (k^T over tokens), slab = 64 rows ----------------

__global__ __launch_bounds__(256) void k_colstats1(const f16* __restrict__ Ckv,
                                                   const float4* __restrict__ stats,
                                                   const float* __restrict__ kg,
                                                   const float* __restrict__ kb,
                                                   float* __restrict__ pm, float* __restrict__ ps) {
    const int b = blockIdx.y, slab = blockIdx.x, t = threadIdx.x;
    const int c0 = t * 2;
    const float g0 = kg[c0], g1 = kg[c0 + 1], e0 = kb[c0], e1 = kb[c0 + 1];
    const size_t r0 = (size_t)b * 8192 + slab * 64;
    float m0 = -1e30f, m1 = -1e30f;
    for (int r = 0; r < 64; r++) {
        const float4 st = stats[r0 + r];
        union { unsigned u; f16 h[2]; } w;
        w.u = *(const unsigned*)(Ckv + (r0 + r) * 1536 + c0);
        const float z0 = ((float)w.h[0] - st.x) * st.y * g0 + e0;
        const float z1 = ((float)w.h[1] - st.x) * st.y * g1 + e1;
        m0 = fmaxf(m0, z0);
        m1 = fmaxf(m1, z1);
    }
    float s0 = 0.f, s1 = 0.f;
    for (int r = 0; r < 64; r++) {
        const float4 st = stats[r0 + r];
        union { unsigned u; f16 h[2]; } w;
        w.u = *(const unsigned*)(Ckv + (r0 + r) * 1536 + c0);
        const float z0 = ((float)w.h[0] - st.x) * st.y * g0 + e0;
        const float z1 = ((float)w.h[1] - st.x) * st.y * g1 + e1;
        s0 += __expf(z0 - m0);
        s1 += __expf(z1 - m1);
    }
    const int o = (b * 128 + slab) * 512 + c0;
    pm[o] = m0; pm[o + 1] = m1;
    ps[o] = s0; ps[o + 1] = s1;
}

__global__ void k_colstats2(const float* __restrict__ pm, const float* __restrict__ ps,
                            float* __restrict__ Mx, float* __restrict__ invZ) {
    const int idx = blockIdx.x * 256 + threadIdx.x;  // 0..4095
    const int b = idx >> 9, c = idx & 511;
    float M = -1e30f;
    for (int s = 0; s < 128; s++) M = fmaxf(M, pm[(b * 128 + s) * 512 + c]);
    float S = 0.f;
    for (int s = 0; s < 128; s++) S += ps[(b * 128 + s) * 512 + c] * __expf(pm[(b * 128 + s) * 512 + c] - M);
    Mx[idx] = M;
    invZ[idx] = 1.0f / S;
}

// ---------------- kv einsum partials over token splits ----------------

__global__ __launch_bounds__(256, 2) void k_kv(const f16* __restrict__ Ckv,
                                               const float4* __restrict__ stats,
                                               const float* __restrict__ kg,
                                               const float* __restrict__ kbe,
                                               const float* __restrict__ vg,
                                               const float* __restrict__ vbe,
                                               const float* __restrict__ Mx,
                                               float* __restrict__ kvpart) {
    __shared__ f16 As[64 * 64];
    __shared__ f16 Vs[128 * 64];
    __shared__ float cgk[64], cbk[64], cmx[64], cgv[128], cbv[128];
    const int split = blockIdx.x, bh = blockIdx.y;
    const int b = bh >> 3, h = bh & 7;
    const int tid = threadIdx.x, lane = tid & 63, wave = tid >> 6;
    if (tid < 64) {
        cgk[tid] = kg[h * 64 + tid];
        cbk[tid] = kbe[h * 64 + tid];
        cmx[tid] = Mx[b * 512 + h * 64 + tid];
    }
    if (tid < 128) {
        cgv[tid] = vg[h * 128 + tid];
        cbv[tid] = vbe[h * 128 + tid];
    }
    __syncthreads();
    f32x4 acc[8] = {};
    const size_t base = (size_t)b * 8192 + split * 1024;
    for (int t0 = 0; t0 < 1024; t0 += 64) {
        {
            const int g = tid & 7, p = tid >> 3;
            const size_t row = base + t0 + 2 * p;
            const f16x8 x0 = *(const f16x8*)(Ckv + row * 1536 + h * 64 + g * 8);
            const f16x8 x1 = *(const f16x8*)(Ckv + (row + 1) * 1536 + h * 64 + g * 8);
            const float4 s0 = stats[row], s1 = stats[row + 1];
#pragma unroll
            for (int j = 0; j < 8; j++) {
                const int c = g * 8 + j;
                const float z0 = ((float)x0[j] - s0.x) * s0.y * cgk[c] + cbk[c] - cmx[c];
                const float z1 = ((float)x1[j] - s1.x) * s1.y * cgk[c] + cbk[c] - cmx[c];
                union { unsigned u; f16 h2[2]; } pk;
                pk.h2[0] = (f16)__expf(z0);
                pk.h2[1] = (f16)__expf(z1);
                *(unsigned*)((char*)As + c * 128 + 4 * p) = pk.u;
            }
        }
#pragma unroll
        for (int sub = 0; sub < 2; sub++) {
            const int idx = tid + sub * 256;
            const int g = idx & 15, p = idx >> 4;
            const size_t row = base + t0 + 2 * p;
            const f16x8 x0 = *(const f16x8*)(Ckv + row * 1536 + 512 + h * 128 + g * 8);
            const f16x8 x1 = *(const f16x8*)(Ckv + (row + 1) * 1536 + 512 + h * 128 + g * 8);
            const float4 s0 = stats[row], s1 = stats[row + 1];
#pragma unroll
            for (int j = 0; j < 8; j++) {
                const int d = g * 8 + j;
                const float z0 = ((float)x0[j] - s0.z) * s0.w * cgv[d] + cbv[d];
                const float z1 = ((float)x1[j] - s1.z) * s1.w * cgv[d] + cbv[d];
                union { unsigned u; f16 h2[2]; } pk;
                pk.h2[0] = (f16)z0;
                pk.h2[1] = (f16)z1;
                *(unsigned*)((char*)Vs + d * 128 + 4 * p) = pk.u;
            }
        }
        __syncthreads();
#pragma unroll
        for (int kk = 0; kk < 64; kk += 32) {
            const int kb2 = (kk + (lane >> 4) * 8) * 2;
            const f16x8 af = *(const f16x8*)((const char*)As + (wave * 16 + (lane & 15)) * 128 + kb2);
#pragma unroll
            for (int ni = 0; ni < 8; ni++) {
                const f16x8 bf = *(const f16x8*)((const char*)Vs + (ni * 16 + (lane & 15)) * 128 + kb2);
                acc[ni] = mfma16(af, bf, acc[ni]);
            }
        }
        __syncthreads();
    }
    float* out = kvpart + ((size_t)split * 64 + bh) * 8192;
    const int l = wave * 16 + (lane >> 4) * 4;
#pragma unroll
    for (int ni = 0; ni < 8; ni++) {
        const int d = ni * 16 + (lane & 15);
#pragma unroll
        for (int j = 0; j < 4; j++) out[(l + j) * 128 + d] = acc[ni][j];
    }
}

__global__ void k_kvreduce(const float* __restrict__ kvpart, const float* __restrict__ invZ,
                           f16* __restrict__ kvT) {
    const int idx = blockIdx.x * 256 + threadIdx.x;
    const int d = idx & 127, l = (idx >> 7) & 63, bh = idx >> 13;
    const int b = bh >> 3, h = bh & 7;
    float s = 0.f;
#pragma unroll
    for (int sp = 0; sp < 8; sp++) s += kvpart[((size_t)sp * 64 + bh) * 8192 + l * 128 + d];
    s *= invZ[b * 512 + h * 64 + l];
    kvT[((size_t)bh * 128 + d) * 64 + l] = (f16)s;
}

// ---------------- q: LN + per-head softmax ----------------

__global__ __launch_bounds__(512) void k_qsm(const f16* __restrict__ qlin,
                                             const float* __restrict__ qg,
                                             const float* __restrict__ qbeta,
                                             f16* __restrict__ qsm) {
    const int row = blockIdx.x, t = threadIdx.x;
    const float x = (float)qlin[(size_t)row * 512 + t];
    float s = x, s2 = x * x;
#pragma unroll
    for (int off = 32; off; off >>= 1) {
        s += __shfl_xor(s, off);
        s2 += __shfl_xor(s2, off);
    }
    __shared__ float rs[16];
    const int wave = t >> 6, lane = t & 63;
    if (lane == 0) {
        rs[wave] = s;
        rs[8 + wave] = s2;
    }
    __syncthreads();
    float S = 0.f, S2 = 0.f;
#pragma unroll
    for (int w = 0; w < 8; w++) {
        S += rs[w];
        S2 += rs[8 + w];
    }
    const float mu = S * (1.0f / 512.0f);
    const float var = S2 * (1.0f / 512.0f) - mu * mu;
    const float z = (x - mu) * rsqrtf(var + LN_EPS) * qg[t] + qbeta[t];
    float m = z;
#pragma unroll
    for (int off = 32; off; off >>= 1) m = fmaxf(m, __shfl_xor(m, off));
    const float e = __expf(z - m);
    float se = e;
#pragma unroll
    for (int off = 32; off; off >>= 1) se += __shfl_xor(se, off);
    qsm[(size_t)row * 512 + t] = (f16)(e / se);
}

// ---------------- out_mid = qsm @ kvT ----------------

__global__ __launch_bounds__(256) void k_qkv(const f16* __restrict__ qsm,
                                             const f16* __restrict__ kvT,
                                             f16* __restrict__ omid) {
    const int ms = blockIdx.x, bh = blockIdx.y;
    const int b = bh >> 3, h = bh & 7;
    const int tid = threadIdx.x, lane = tid & 63, wave = tid >> 6;
    const int mr = ms * 64 + wave * 16;
    f32x4 acc[8] = {};
    const f16* Ab = qsm + (size_t)(b * 256 + mr + (lane & 15)) * 512 + h * 64;
    const f16* Bb = kvT + (size_t)bh * 8192;
#pragma unroll
    for (int kk = 0; kk < 64; kk += 32) {
        const int k = kk + (lane >> 4) * 8;
        const f16x8 af = *(const f16x8*)(Ab + k);
#pragma unroll
        for (int ni = 0; ni < 8; ni++) {
            const f16x8 bf = *(const f16x8*)(Bb + (ni * 16 + (lane & 15)) * 64 + k);
            acc[ni] = mfma16(af, bf, acc[ni]);
        }
    }
    const int r = b * 256 + mr + (lane >> 4) * 4;
#pragma unroll
    for (int ni = 0; ni < 8; ni++) {
        const int d = h * 128 + ni * 16 + (lane & 15);
#pragma unroll
        for (int j = 0; j < 4; j++) omid[(size_t)(r + j) * 1024 + d] = (f16)acc[ni][j];
    }
}

// ---------------- launch ----------------

extern "C" void kernel_launch(void* const* d_in, const int* in_sizes, int n_in,
                              void* d_out, int out_size, void* d_ws, size_t ws_size,
                              hipStream_t stream) {
    const float* input  = (const float*)d_in[0];
    const float* query  = (const float*)d_in[1];
    const float* q_w    = (const float*)d_in[2];
    const float* q_b    = (const float*)d_in[3];
    const float* q_g    = (const float*)d_in[4];
    const float* q_beta = (const float*)d_in[5];
    const float* k_w    = (const float*)d_in[6];
    const float* k_b    = (const float*)d_in[7];
    const float* k_g    = (const float*)d_in[8];
    const float* k_beta = (const float*)d_in[9];
    const float* v_w    = (const float*)d_in[10];
    const float* v_b    = (const float*)d_in[11];
    const float* v_g    = (const float*)d_in[12];
    const float* v_beta = (const float*)d_in[13];
    const float* proj_w = (const float*)d_in[14];
    const float* proj_b = (const float*)d_in[15];

    char* ws = (char*)d_ws;
    size_t off = 0;
    auto alloc = [&](size_t bytes) {
        char* p = ws + off;
        off += (bytes + 255) & ~(size_t)255;
        return p;
    };
    f16*   A16    = (f16*)alloc((size_t)67108864 * 2);
    f16*   Q16    = (f16*)alloc((size_t)2097152 * 2);
    f16*   BkvT   = (f16*)alloc((size_t)1536 * 1024 * 2);
    f16*   qwT    = (f16*)alloc((size_t)512 * 1024 * 2);
    f16*   pwT    = (f16*)alloc((size_t)1024 * 1024 * 2);
    f16*   Ckv    = (f16*)alloc((size_t)65536 * 1536 * 2);
    float* stats  = (float*)alloc((size_t)65536 * 16);
    float* pm     = (float*)alloc((size_t)8 * 128 * 512 * 4);
    float* ps     = (float*)alloc((size_t)8 * 128 * 512 * 4);
    float* Mx     = (float*)alloc((size_t)8 * 512 * 4);
    float* invZ   = (float*)alloc((size_t)8 * 512 * 4);
    f16*   qlin   = (f16*)alloc((size_t)2048 * 512 * 2);
    f16*   qsm    = (f16*)alloc((size_t)2048 * 512 * 2);
    float* kvpart = (float*)alloc((size_t)8 * 64 * 64 * 128 * 4);
    f16*   kvT    = (f16*)alloc((size_t)64 * 128 * 64 * 2);
    f16*   omid   = (f16*)alloc((size_t)2048 * 1024 * 2);
    (void)ws_size; (void)in_sizes; (void)n_in; (void)out_size;

    hipFuncSetAttribute(reinterpret_cast<const void*>(k_gemm256),
                        hipFuncAttributeMaxDynamicSharedMemorySize, 131072);

    // 1) converts + weight transposes
    k_cvt_dual<<<2048, 256, 0, stream>>>((const float4*)input, (const float4*)query,
                                         (f16x4*)A16, (f16x4*)Q16, 16777216, 17301504);
    k_transpose_all<<<dim3(96, 32), 256, 0, stream>>>(k_w, v_w, q_w, proj_w, BkvT, qwT, pwT);

    // 2) fused K/V projection GEMM (256^2 tile, 8-wave pipelined)
    k_gemm256<<<1536, 512, 131072, stream>>>(A16, BkvT, Ckv, k_b, v_b);

    // 3) row LN stats
    k_rowstats<<<65536, 192, 0, stream>>>(Ckv, stats);

    // 4) column softmax stats for k^T
    k_colstats1<<<dim3(128, 8), 256, 0, stream>>>(Ckv, (const float4*)stats, k_g, k_beta, pm, ps);
    k_colstats2<<<16, 256, 0, stream>>>(pm, ps, Mx, invZ);

    // 5) kv einsum + reduce
    k_kv<<<dim3(8, 64), 256, 0, stream>>>(Ckv, (const float4*)stats, k_g, k_beta, v_g, v_beta, Mx, kvpart);
    k_kvreduce<<<2048, 256, 0, stream>>>(kvpart, invZ, kvT);

    // 6) q path
    k_gemm<false><<<dim3(4, 16), 256, 0, stream>>>(Q16, qwT, qlin, 512, 1024, q_b, q_b, 512);
    k_qsm<<<2048, 512, 0, stream>>>(qlin, q_g, q_beta, qsm);
    k_qkv<<<dim3(4, 64), 256, 0, stream>>>(qsm, kvT, omid);
    k_gemm<true><<<dim3(8, 16), 256, 0, stream>>>(omid, pwT, d_out, 1024, 1024, proj_b, proj_b, 2048);
}